// Round 12
// baseline (603.931 us; speedup 1.0000x reference)
//
#include <hip/hip_runtime.h>
#include <hip/hip_fp16.h>

// Node_Embedding: HeteroGraphConv(sum) of 4 GraphConv relations + PReLU.
// Pipeline: k_cvt (x->fp16) ; k_hist (LDS packed-u16 histograms, no global
// atomics -> cntin + coef) ; 3-phase scan -> CSR offs ; k_fill2 (LDS-cursor
// counting-sort placement) ; k_gather (latency-optimized fp16 edge gather,
// agg in-place in d_out) ; k_gemm (dense MFMA f16 GEMM + bias + PReLU).
// k_gather at 6 blocks/CU: 8 blocks/CU thrashes L2 (R8: 187->275us).

#define NB 50000   // nodes per type
#define EB 500000  // edges per relation
#define D  128
#define NCH 98     // ceil(NB/512)
#define CAP 512    // LDS edge-window capacity per relation (mean 160)
#define HR 12500   // histogram node-range per block (25KB LDS packed)
#define FR 6250    // fill cursor node-range per block (25KB LDS)

struct EdgePtrs { const int* src[4]; const int* dst[4]; };

typedef _Float16 f16x8 __attribute__((ext_vector_type(8)));
typedef float f32x4 __attribute__((ext_vector_type(4)));
typedef unsigned int u32x4 __attribute__((ext_vector_type(4)));

__device__ inline float hlo(unsigned u) {
    return __half2float(__ushort_as_half((unsigned short)(u & 0xffffu)));
}
__device__ inline float hhi(unsigned u) {
    return __half2float(__ushort_as_half((unsigned short)(u >> 16)));
}

// x (fp32) -> fp16, float4/thread.
__global__ __launch_bounds__(256) void k_cvt(const float* __restrict__ xd,
                                             const float* __restrict__ xs,
                                             unsigned short* __restrict__ xh) {
    int i = blockIdx.x * 256 + threadIdx.x;   // float4 index, 3.2M total
    const int half = NB * D / 4;
    const float* src = (i < half) ? xd : xs;
    int j = (i < half) ? i : i - half;
    float4 v = reinterpret_cast<const float4*>(src)[j];
    ushort4 o;
    o.x = __half_as_ushort(__float2half(v.x));
    o.y = __half_as_ushort(__float2half(v.y));
    o.z = __half_as_ushort(__float2half(v.z));
    o.w = __half_as_ushort(__float2half(v.w));
    reinterpret_cast<ushort4*>(xh)[i] = o;
}

// LDS histogram: block (range, rel, io) counts endpoints in [lo, lo+HR).
// Packed u16 pairs (max degree ~40 << 65535). io=0: in-degree -> cntin;
// io=1: out-degree -> coef = rsqrt(max(deg,1)).
__global__ __launch_bounds__(1024) void k_hist(EdgePtrs ep,
                                               int* __restrict__ cntin,
                                               float* __restrict__ coef) {
    __shared__ unsigned pk[HR / 2];
    const int range = blockIdx.x, rel = blockIdx.y, io = blockIdx.z;
    const int lo = range * HR;
    const int* arr = io ? ep.src[rel] : ep.dst[rel];
    for (int i = threadIdx.x; i < HR / 2; i += 1024) pk[i] = 0;
    __syncthreads();
    for (int i = threadIdx.x; i < EB / 4; i += 1024) {
        int4 v = reinterpret_cast<const int4*>(arr)[i];
#pragma unroll
        for (int k = 0; k < 4; ++k) {
            int n = (&v.x)[k] - lo;
            if ((unsigned)n < (unsigned)HR)
                atomicAdd(&pk[n >> 1], 1u << (16 * (n & 1)));
        }
    }
    __syncthreads();
    if (io == 0) {
        for (int i = threadIdx.x; i < HR / 2; i += 1024) {
            unsigned p = pk[i];
            cntin[rel * NB + lo + 2 * i]     = p & 0xffffu;
            cntin[rel * NB + lo + 2 * i + 1] = p >> 16;
        }
    } else {
        for (int i = threadIdx.x; i < HR / 2; i += 1024) {
            unsigned p = pk[i];
            int c0 = p & 0xffffu, c1 = p >> 16;
            coef[rel * NB + lo + 2 * i]     = rsqrtf((float)(c0 > 1 ? c0 : 1));
            coef[rel * NB + lo + 2 * i + 1] = rsqrtf((float)(c1 > 1 ? c1 : 1));
        }
    }
}

// Pack W (fp32 [4][128][128]) into MFMA B-fragment order, fp16.
__global__ __launch_bounds__(256) void k_wpack(const float* __restrict__ W,
                                               _Float16* __restrict__ Wb) {
    int idx = blockIdx.x * 256 + threadIdx.x;   // 8192 total
    int t = idx >> 12, jt = (idx >> 9) & 7, ks = (idx >> 6) & 7, l = idx & 63;
    int col = jt * 16 + (l & 15);
    int kb = ks * 32 + (l >> 4) * 8;
    _Float16 h[8];
#pragma unroll
    for (int m = 0; m < 8; ++m) {
        int k = kb + m;
        int r = (k < 128) ? t : (2 + t);
        h[m] = (_Float16)W[r * D * D + (k & 127) * D + col];
    }
    *reinterpret_cast<f16x8*>(Wb + (size_t)idx * 8) = *reinterpret_cast<f16x8*>(h);
}

// Phase 1: per-chunk (512 nodes) exclusive scan of in-degrees.
__global__ __launch_bounds__(512) void k_scan1(const int* __restrict__ cntin,
                                               int* __restrict__ offs,
                                               int* __restrict__ chunksum) {
    int r = blockIdx.y, c = blockIdx.x, t = threadIdx.x;
    int node = c * 512 + t;
    int v = (node < NB) ? cntin[r * NB + node] : 0;
    __shared__ int sh[512];
    sh[t] = v;
    __syncthreads();
    for (int off = 1; off < 512; off <<= 1) {
        int u = (t >= off) ? sh[t - off] : 0;
        __syncthreads();
        sh[t] += u;
        __syncthreads();
    }
    int incl = sh[t];
    if (node < NB) offs[r * (NB + 1) + node] = incl - v;  // local exclusive
    if (t == 511) chunksum[r * NCH + c] = incl;
}

// Phase 2: exclusive scan of the NCH chunk totals per relation (wave r).
__global__ __launch_bounds__(256) void k_scan2(int* __restrict__ chunksum) {
    int r = threadIdx.x >> 6, lane = threadIdx.x & 63;
    int* cs = chunksum + r * NCH;
    int s0 = cs[lane];
    int s1 = (64 + lane < NCH) ? cs[64 + lane] : 0;
    int x = s0;
    for (int d = 1; d < 64; d <<= 1) { int u = __shfl_up(x, d, 64); if (lane >= d) x += u; }
    int tot0 = __shfl(x, 63, 64);
    int y = s1;
    for (int d = 1; d < 64; d <<= 1) { int u = __shfl_up(y, d, 64); if (lane >= d) y += u; }
    y += tot0;
    cs[lane] = x - s0;
    if (64 + lane < NCH) cs[64 + lane] = y - s1;
}

// Phase 3: add chunk base; offs[NB] = EB.
__global__ __launch_bounds__(512) void k_scan3(int* __restrict__ offs,
                                               const int* __restrict__ chunksum) {
    int r = blockIdx.y, c = blockIdx.x, t = threadIdx.x;
    int node = c * 512 + t;
    if (node < NB)
        offs[r * (NB + 1) + node] += chunksum[r * NCH + c];
    if (c == NCH - 1 && t == 0) offs[r * (NB + 1) + NB] = EB;
}

// Counting-sort placement with LDS cursors: block (range, rel) streams the
// whole edge list, placing edges whose dst is in [lo, lo+FR). No global
// atomics; rank order within a dst is arbitrary (fp-sum reorder only).
__global__ __launch_bounds__(1024) void k_fill2(EdgePtrs ep,
                                                const float* __restrict__ coef,
                                                const int* __restrict__ offs,
                                                int2* __restrict__ epack) {
    __shared__ int cur[FR];
    const int lo = blockIdx.x * FR, rel = blockIdx.y;
    const int* srcA = ep.src[rel];
    const int* dstA = ep.dst[rel];
    const float* cf = coef + rel * NB;
    int2* epk = epack + (size_t)rel * EB;
    for (int i = threadIdx.x; i < FR; i += 1024)
        cur[i] = offs[rel * (NB + 1) + lo + i];
    __syncthreads();
    for (int i = threadIdx.x; i < EB / 2; i += 1024) {
        int2 d2 = reinterpret_cast<const int2*>(dstA)[i];
        int2 s2 = reinterpret_cast<const int2*>(srcA)[i];
        int n0 = d2.x - lo;
        if ((unsigned)n0 < (unsigned)FR) {
            int pos = atomicAdd(&cur[n0], 1);
            epk[pos] = make_int2(s2.x, __float_as_int(cf[s2.x]));
        }
        int n1 = d2.y - lo;
        if ((unsigned)n1 < (unsigned)FR) {
            int pos = atomicAdd(&cur[n1], 1);
            epk[pos] = make_int2(s2.y, __float_as_int(cf[s2.y]));
        }
    }
}

#define PREF(ii, c0, c1, c2, c3, r0, r1, r2, r3)                               \
    {                                                                          \
        int j1 = (ii) + 1 < ghi ? (ii) + 1 : ghi - 1;                          \
        int j2 = (ii) + 2 < ghi ? (ii) + 2 : ghi - 1;                          \
        int j3 = (ii) + 3 < ghi ? (ii) + 3 : ghi - 1;                          \
        int2 q0 = eb[(ii)], q1 = eb[j1], q2 = eb[j2], q3 = eb[j3];             \
        c0 = __int_as_float(q0.y);                                             \
        c1 = ((ii) + 1 < ghi) ? __int_as_float(q1.y) : 0.f;                    \
        c2 = ((ii) + 2 < ghi) ? __int_as_float(q2.y) : 0.f;                    \
        c3 = ((ii) + 3 < ghi) ? __int_as_float(q3.y) : 0.f;                    \
        r0 = *reinterpret_cast<const uint4*>(x + ((unsigned)q0.x * D + cbase));\
        r1 = *reinterpret_cast<const uint4*>(x + ((unsigned)q1.x * D + cbase));\
        r2 = *reinterpret_cast<const uint4*>(x + ((unsigned)q2.x * D + cbase));\
        r3 = *reinterpret_cast<const uint4*>(x + ((unsigned)q3.x * D + cbase));\
    }

#define FMA8(c, r)                                                             \
    {                                                                          \
        acc[0] = fmaf(hlo(r.x), c, acc[0]); acc[1] = fmaf(hhi(r.x), c, acc[1]);\
        acc[2] = fmaf(hlo(r.y), c, acc[2]); acc[3] = fmaf(hhi(r.y), c, acc[3]);\
        acc[4] = fmaf(hlo(r.z), c, acc[4]); acc[5] = fmaf(hhi(r.z), c, acc[5]);\
        acc[6] = fmaf(hlo(r.w), c, acc[6]); acc[7] = fmaf(hhi(r.w), c, acc[7]);\
    }

// Pure gather: 16 rows/block, 16-lane groups, pipelined; writes fp16 agg
// (cols 0-127 rel A, 128-255 rel B) in-place into d_out via NT stores.
__global__ __launch_bounds__(256, 6) void k_gather(
    const unsigned short* __restrict__ xh,  // [2][NB][D] fp16: drug then dis
    const int* __restrict__ offs, const int2* __restrict__ epack,
    unsigned short* __restrict__ agg) {     // [2*NB][256] fp16 (aliases d_out)
    __shared__ int2 ebuf[2][CAP];
    __shared__ int soff[2][17];
    const int t = blockIdx.y;
    const int row0 = blockIdx.x * 16;
    const int tid = threadIdx.x;
    const int g = tid >> 4, l16 = tid & 15;
    const int cbase = l16 * 8;          // this lane's 8 fp16 columns

    if (tid < 34) {
        int h = tid / 17, k = tid % 17;
        int rel = h ? (2 + t) : t;
        soff[h][k] = offs[rel * (NB + 1) + row0 + k];
    }
    __syncthreads();

    // stage both relations' edge windows (first CAP each); non-temporal.
    for (int h = 0; h < 2; ++h) {
        int rel = h ? (2 + t) : t;
        const long long* epk =
            reinterpret_cast<const long long*>(epack + (size_t)rel * EB);
        int base = soff[h][0];
        int tot = soff[h][16] - base; if (tot > CAP) tot = CAP;
        for (int i = tid; i < tot; i += 256) {
            long long v = __builtin_nontemporal_load(&epk[base + i]);
            ebuf[h][i] = make_int2((int)(v & 0xffffffffLL), (int)(v >> 32));
        }
    }
    __syncthreads();

    for (int h = 0; h < 2; ++h) {
        int rel = h ? (2 + t) : t;
        const unsigned short* x = xh + (size_t)h * NB * D;
        const int2* epk = epack + (size_t)rel * EB;
        const int base = soff[h][0];
        const int glo = soff[h][g] - base;
        const int ghi0 = soff[h][g + 1] - base;
        const int ghi = ghi0 < CAP ? ghi0 : CAP;   // LDS-resident part
        const int2* eb = ebuf[h];
        float acc[8] = {0.f, 0.f, 0.f, 0.f, 0.f, 0.f, 0.f, 0.f};

        if (glo < ghi) {
            uint4 rA0, rA1, rA2, rA3, rB0, rB1, rB2, rB3;
            float cA0, cA1, cA2, cA3, cB0, cB1, cB2, cB3;
            PREF(glo, cA0, cA1, cA2, cA3, rA0, rA1, rA2, rA3);
            for (int i = glo; i < ghi; i += 8) {
                bool hasB = (i + 4 < ghi);
                if (hasB) PREF(i + 4, cB0, cB1, cB2, cB3, rB0, rB1, rB2, rB3);
                FMA8(cA0, rA0); FMA8(cA1, rA1); FMA8(cA2, rA2); FMA8(cA3, rA3);
                if (i + 8 < ghi) PREF(i + 8, cA0, cA1, cA2, cA3, rA0, rA1, rA2, rA3);
                if (hasB) { FMA8(cB0, rB0); FMA8(cB1, rB1); FMA8(cB2, rB2); FMA8(cB3, rB3); }
            }
        }
        // rare overflow tail straight from global
        for (int i = (glo > CAP ? glo : CAP); i < ghi0; ++i) {
            int2 p = epk[base + i];
            float cc = __int_as_float(p.y);
            uint4 rr = *reinterpret_cast<const uint4*>(x + ((unsigned)p.x * D + cbase));
            FMA8(cc, rr);
        }
        int dg = ghi0 - glo;
        float di = rsqrtf((float)(dg > 1 ? dg : 1));
        u32x4 q;
#pragma unroll
        for (int k2 = 0; k2 < 4; ++k2) {
            unsigned lo2 = __half_as_ushort(__float2half(acc[2 * k2] * di));
            unsigned hi2 = __half_as_ushort(__float2half(acc[2 * k2 + 1] * di));
            q[k2] = lo2 | (hi2 << 16);
        }
        u32x4* dst = reinterpret_cast<u32x4*>(
            agg + ((size_t)(t * NB + row0 + g) * 256 + h * 128 + cbase));
        __builtin_nontemporal_store(q, dst);
    }
}

// Dense MFMA GEMM: out[r][j] = prelu(sum_k agg[r][k] * Wcat_t[k][j] + bias).
__global__ __launch_bounds__(256) void k_gemm(
    const _Float16* agg,                    // aliases out
    const _Float16* __restrict__ Wb,
    const float* __restrict__ b, const float* __restrict__ prelu_a,
    float* out) {
    const int t = blockIdx.y;
    const int tid = threadIdx.x, w = tid >> 6, l = tid & 63;
    const int rbase = t * NB + blockIdx.x * 64 + w * 16;
    const int rmax = t * NB + NB - 1;
    const int lk = (l >> 4) * 8;
    f32x4 acc[8] = {};
    const f16x8* wb = reinterpret_cast<const f16x8*>(Wb + (size_t)t * 32768);
    int ra = rbase + (l & 15); if (ra > rmax) ra = rmax;
    const _Float16* ap = agg + (size_t)ra * 256 + lk;
#pragma unroll
    for (int ks = 0; ks < 8; ++ks) {
        f16x8 a = *reinterpret_cast<const f16x8*>(ap + ks * 32);
#pragma unroll
        for (int jt = 0; jt < 8; ++jt) {
            f16x8 bf = wb[(jt * 8 + ks) * 64 + l];
            acc[jt] = __builtin_amdgcn_mfma_f32_16x16x32_f16(a, bf, acc[jt], 0, 0, 0);
        }
    }
    float pa = prelu_a[0];
    const int rowoff = (l >> 4) * 4;
#pragma unroll
    for (int jt = 0; jt < 8; ++jt) {
        int col = jt * 16 + (l & 15);
        float bs = b[t * D + col] + b[(2 + t) * D + col];
#pragma unroll
        for (int m = 0; m < 4; ++m) {
            int grow = rbase + rowoff + m;
            if (grow <= rmax) {
                float v = acc[jt][m] + bs;
                v = v >= 0.f ? v : pa * v;
                out[(size_t)grow * D + col] = v;
            }
        }
    }
}

extern "C" void kernel_launch(void* const* d_in, const int* in_sizes, int n_in,
                              void* d_out, int out_size, void* d_ws, size_t ws_size,
                              hipStream_t stream) {
    const float* x_drug = (const float*)d_in[0];
    const float* x_dis  = (const float*)d_in[1];
    const float* W      = (const float*)d_in[2];   // [4,128,128]
    const float* b      = (const float*)d_in[3];   // [4,128]
    const float* pa     = (const float*)d_in[4];   // [1]
    EdgePtrs ep;
    ep.src[0] = (const int*)d_in[5];  ep.dst[0] = (const int*)d_in[6];   // dd
    ep.src[1] = (const int*)d_in[7];  ep.dst[1] = (const int*)d_in[8];   // ds
    ep.src[2] = (const int*)d_in[9];  ep.dst[2] = (const int*)d_in[10];  // sd
    ep.src[3] = (const int*)d_in[11]; ep.dst[3] = (const int*)d_in[12];  // ss

    // workspace layout (bytes); no memset needed — all buffers fully written
    char* ws = (char*)d_ws;
    int*   cntin    = (int*)(ws + 0);          // [4][NB]
    float* coef     = (float*)(ws + 800000);   // [4][NB]
    int*   offs     = (int*)(ws + 1600000);    // [4][NB+1]
    int*   chunksum = (int*)(ws + 2400064);    // [4][NCH]
    int2*  epack    = (int2*)(ws + 2401664);   // [4][EB] int2 (16 MB)
    unsigned short* xh = (unsigned short*)(ws + 18401664);  // fp16 x (25.6 MB)
    _Float16* Wb    = (_Float16*)(ws + 44001664); // 128 KB packed W
    // total ~44.2 MB

    k_cvt<<<12500, 256, 0, stream>>>(x_drug, x_dis, xh);
    k_hist<<<dim3(4, 4, 2), 1024, 0, stream>>>(ep, cntin, coef);
    k_wpack<<<32, 256, 0, stream>>>(W, Wb);
    k_scan1<<<dim3(NCH, 4), 512, 0, stream>>>(cntin, offs, chunksum);
    k_scan2<<<1, 256, 0, stream>>>(chunksum);
    k_scan3<<<dim3(NCH, 4), 512, 0, stream>>>(offs, chunksum);
    k_fill2<<<dim3(8, 4), 1024, 0, stream>>>(ep, coef, offs, epack);
    k_gather<<<dim3(NB / 16, 2), 256, 0, stream>>>(
        xh, offs, epack, (unsigned short*)d_out);
    k_gemm<<<dim3(782, 2), 256, 0, stream>>>(
        (const _Float16*)d_out, Wb, b, pa, (float*)d_out);
}

// Round 13
// 337.860 us; speedup vs baseline: 1.7875x; 1.7875x over previous
//
#include <hip/hip_runtime.h>
#include <hip/hip_fp16.h>

// Node_Embedding: HeteroGraphConv(sum) of 4 GraphConv relations + PReLU.
// Pipeline (no global atomics, no memsets):
//   k_cvt (x->fp16) ; k_hist (chunk x range LDS u16 histograms -> per-chunk
//   counts) ; k_scan1..3 (chunk-prefix + CSR offs + coef) ; k_fill3
//   (chunk x range LDS-cursor counting-sort placement) ; k_gather (latency-
//   optimized fp16 edge gather, agg in d_out) ; k_gemm (MFMA f16 + PReLU).
// k_gather at 6 blocks/CU: 8 blocks/CU thrashes L2 (R8: 187->275us).
// R12 lesson: any kernel streaming the WHOLE edge list from few blocks is
// per-CU-BW bound (307us at 5% occupancy) -> chunk everything.

#define NB 50000   // nodes per type
#define EB 500000  // edges per relation
#define D  128
#define NCH 98     // ceil(NB/512)
#define CAP 512    // gather LDS edge-window capacity per relation (mean 160)
#define NCHK 16    // edge chunks
#define CH2 15625  // (EB/NCHK)/2 int2 loads per chunk
#define NRG 8      // node ranges
#define FR 6250    // nodes per range

struct EdgePtrs { const int* src[4]; const int* dst[4]; };

typedef _Float16 f16x8 __attribute__((ext_vector_type(8)));
typedef float f32x4 __attribute__((ext_vector_type(4)));
typedef unsigned int u32x4 __attribute__((ext_vector_type(4)));

__device__ inline float hlo(unsigned u) {
    return __half2float(__ushort_as_half((unsigned short)(u & 0xffffu)));
}
__device__ inline float hhi(unsigned u) {
    return __half2float(__ushort_as_half((unsigned short)(u >> 16)));
}

// x (fp32) -> fp16, float4/thread.
__global__ __launch_bounds__(256) void k_cvt(const float* __restrict__ xd,
                                             const float* __restrict__ xs,
                                             unsigned short* __restrict__ xh) {
    int i = blockIdx.x * 256 + threadIdx.x;   // float4 index, 3.2M total
    const int half = NB * D / 4;
    const float* src = (i < half) ? xd : xs;
    int j = (i < half) ? i : i - half;
    float4 v = reinterpret_cast<const float4*>(src)[j];
    ushort4 o;
    o.x = __half_as_ushort(__float2half(v.x));
    o.y = __half_as_ushort(__float2half(v.y));
    o.z = __half_as_ushort(__float2half(v.z));
    o.w = __half_as_ushort(__float2half(v.w));
    reinterpret_cast<ushort4*>(xh)[i] = o;
}

// Chunked LDS histogram. Block (chunk, range, z) with z = io*4 + rel:
// counts endpoints of its edge chunk falling in [lo, lo+FR).
// io=0 -> cnt2in[rel][chunk][*], io=1 -> cnt2o[rel][chunk][*] (u16).
__global__ __launch_bounds__(256) void k_hist(EdgePtrs ep,
                                              unsigned short* __restrict__ cnt2in,
                                              unsigned short* __restrict__ cnt2o) {
    __shared__ unsigned pk[FR / 2];   // packed u16 pairs, 12.5 KB
    const int chunk = blockIdx.x, range = blockIdx.y;
    const int rel = blockIdx.z & 3, io = blockIdx.z >> 2;
    const int lo = range * FR;
    const int* arr = io ? ep.src[rel] : ep.dst[rel];
    for (int i = threadIdx.x; i < FR / 2; i += 256) pk[i] = 0;
    __syncthreads();
    const int2* a2 = reinterpret_cast<const int2*>(arr) + (size_t)chunk * CH2;
    for (int i = threadIdx.x; i < CH2; i += 256) {
        int2 v = a2[i];
        int n0 = v.x - lo;
        if ((unsigned)n0 < (unsigned)FR) atomicAdd(&pk[n0 >> 1], 1u << (16 * (n0 & 1)));
        int n1 = v.y - lo;
        if ((unsigned)n1 < (unsigned)FR) atomicAdd(&pk[n1 >> 1], 1u << (16 * (n1 & 1)));
    }
    __syncthreads();
    unsigned short* out = io ? cnt2o : cnt2in;
    unsigned* dst = reinterpret_cast<unsigned*>(out + ((size_t)(rel * NCHK + chunk)) * NB);
    for (int i = threadIdx.x; i < FR / 2; i += 256) dst[lo / 2 + i] = pk[i];
}

// Pack W (fp32 [4][128][128]) into MFMA B-fragment order, fp16.
__global__ __launch_bounds__(256) void k_wpack(const float* __restrict__ W,
                                               _Float16* __restrict__ Wb) {
    int idx = blockIdx.x * 256 + threadIdx.x;   // 8192 total
    int t = idx >> 12, jt = (idx >> 9) & 7, ks = (idx >> 6) & 7, l = idx & 63;
    int col = jt * 16 + (l & 15);
    int kb = ks * 32 + (l >> 4) * 8;
    _Float16 h[8];
#pragma unroll
    for (int m = 0; m < 8; ++m) {
        int k = kb + m;
        int r = (k < 128) ? t : (2 + t);
        h[m] = (_Float16)W[r * D * D + (k & 127) * D + col];
    }
    *reinterpret_cast<f16x8*>(Wb + (size_t)idx * 8) = *reinterpret_cast<f16x8*>(h);
}

// Phase 1: per node — chunk-prefix cnt2in in place (u16), outdeg sum -> coef,
// then per-chunk-of-512-nodes exclusive block scan of total in-degree.
__global__ __launch_bounds__(512) void k_scan1(unsigned short* __restrict__ cnt2in,
                                               const unsigned short* __restrict__ cnt2o,
                                               float* __restrict__ coef,
                                               int* __restrict__ offs,
                                               int* __restrict__ chunksum) {
    int r = blockIdx.y, c = blockIdx.x, t = threadIdx.x;
    int node = c * 512 + t;
    int v = 0;
    if (node < NB) {
        int tin = 0;
#pragma unroll
        for (int k = 0; k < NCHK; ++k) {
            size_t idx = ((size_t)(r * NCHK + k)) * NB + node;
            int cc = cnt2in[idx];
            cnt2in[idx] = (unsigned short)tin;   // exclusive chunk prefix
            tin += cc;
        }
        v = tin;
        int tout = 0;
#pragma unroll
        for (int k = 0; k < NCHK; ++k)
            tout += cnt2o[((size_t)(r * NCHK + k)) * NB + node];
        coef[r * NB + node] = rsqrtf((float)(tout > 1 ? tout : 1));
    }
    __shared__ int sh[512];
    sh[t] = v;
    __syncthreads();
    for (int off = 1; off < 512; off <<= 1) {
        int u = (t >= off) ? sh[t - off] : 0;
        __syncthreads();
        sh[t] += u;
        __syncthreads();
    }
    int incl = sh[t];
    if (node < NB) offs[r * (NB + 1) + node] = incl - v;  // local exclusive
    if (t == 511) chunksum[r * NCH + c] = incl;
}

// Phase 2: exclusive scan of the NCH chunk totals per relation (wave r).
__global__ __launch_bounds__(256) void k_scan2(int* __restrict__ chunksum) {
    int r = threadIdx.x >> 6, lane = threadIdx.x & 63;
    int* cs = chunksum + r * NCH;
    int s0 = cs[lane];
    int s1 = (64 + lane < NCH) ? cs[64 + lane] : 0;
    int x = s0;
    for (int d = 1; d < 64; d <<= 1) { int u = __shfl_up(x, d, 64); if (lane >= d) x += u; }
    int tot0 = __shfl(x, 63, 64);
    int y = s1;
    for (int d = 1; d < 64; d <<= 1) { int u = __shfl_up(y, d, 64); if (lane >= d) y += u; }
    y += tot0;
    cs[lane] = x - s0;
    if (64 + lane < NCH) cs[64 + lane] = y - s1;
}

// Phase 3: add chunk base; offs[NB] = EB.
__global__ __launch_bounds__(512) void k_scan3(int* __restrict__ offs,
                                               const int* __restrict__ chunksum) {
    int r = blockIdx.y, c = blockIdx.x, t = threadIdx.x;
    int node = c * 512 + t;
    if (node < NB)
        offs[r * (NB + 1) + node] += chunksum[r * NCH + c];
    if (c == NCH - 1 && t == 0) offs[r * (NB + 1) + NB] = EB;
}

// Chunked counting-sort placement. Block (chunk, range, rel): LDS cursors =
// offs + chunk-prefix; streams only its chunk; places in-range edges.
__global__ __launch_bounds__(256) void k_fill3(EdgePtrs ep,
                                               const unsigned short* __restrict__ cnt2in,
                                               const float* __restrict__ coef,
                                               const int* __restrict__ offs,
                                               int2* __restrict__ epack) {
    __shared__ int cur[FR];           // 25 KB
    const int chunk = blockIdx.x, range = blockIdx.y, rel = blockIdx.z;
    const int lo = range * FR;
    const unsigned short* pre = cnt2in + ((size_t)(rel * NCHK + chunk)) * NB;
    for (int i = threadIdx.x; i < FR; i += 256)
        cur[i] = offs[rel * (NB + 1) + lo + i] + pre[lo + i];
    __syncthreads();
    const int2* d2p = reinterpret_cast<const int2*>(ep.dst[rel]) + (size_t)chunk * CH2;
    const int2* s2p = reinterpret_cast<const int2*>(ep.src[rel]) + (size_t)chunk * CH2;
    const float* cf = coef + rel * NB;
    int2* epk = epack + (size_t)rel * EB;
    for (int i = threadIdx.x; i < CH2; i += 256) {
        int2 d2 = d2p[i];
        int2 s2 = s2p[i];
        int n0 = d2.x - lo;
        if ((unsigned)n0 < (unsigned)FR) {
            int pos = atomicAdd(&cur[n0], 1);
            epk[pos] = make_int2(s2.x, __float_as_int(cf[s2.x]));
        }
        int n1 = d2.y - lo;
        if ((unsigned)n1 < (unsigned)FR) {
            int pos = atomicAdd(&cur[n1], 1);
            epk[pos] = make_int2(s2.y, __float_as_int(cf[s2.y]));
        }
    }
}

#define PREF(ii, c0, c1, c2, c3, r0, r1, r2, r3)                               \
    {                                                                          \
        int j1 = (ii) + 1 < ghi ? (ii) + 1 : ghi - 1;                          \
        int j2 = (ii) + 2 < ghi ? (ii) + 2 : ghi - 1;                          \
        int j3 = (ii) + 3 < ghi ? (ii) + 3 : ghi - 1;                          \
        int2 q0 = eb[(ii)], q1 = eb[j1], q2 = eb[j2], q3 = eb[j3];             \
        c0 = __int_as_float(q0.y);                                             \
        c1 = ((ii) + 1 < ghi) ? __int_as_float(q1.y) : 0.f;                    \
        c2 = ((ii) + 2 < ghi) ? __int_as_float(q2.y) : 0.f;                    \
        c3 = ((ii) + 3 < ghi) ? __int_as_float(q3.y) : 0.f;                    \
        r0 = *reinterpret_cast<const uint4*>(x + ((unsigned)q0.x * D + cbase));\
        r1 = *reinterpret_cast<const uint4*>(x + ((unsigned)q1.x * D + cbase));\
        r2 = *reinterpret_cast<const uint4*>(x + ((unsigned)q2.x * D + cbase));\
        r3 = *reinterpret_cast<const uint4*>(x + ((unsigned)q3.x * D + cbase));\
    }

#define FMA8(c, r)                                                             \
    {                                                                          \
        acc[0] = fmaf(hlo(r.x), c, acc[0]); acc[1] = fmaf(hhi(r.x), c, acc[1]);\
        acc[2] = fmaf(hlo(r.y), c, acc[2]); acc[3] = fmaf(hhi(r.y), c, acc[3]);\
        acc[4] = fmaf(hlo(r.z), c, acc[4]); acc[5] = fmaf(hhi(r.z), c, acc[5]);\
        acc[6] = fmaf(hlo(r.w), c, acc[6]); acc[7] = fmaf(hhi(r.w), c, acc[7]);\
    }

// Pure gather: 16 rows/block, 16-lane groups, pipelined; writes fp16 agg
// (cols 0-127 rel A, 128-255 rel B) in-place into d_out via NT stores.
__global__ __launch_bounds__(256, 6) void k_gather(
    const unsigned short* __restrict__ xh,  // [2][NB][D] fp16: drug then dis
    const int* __restrict__ offs, const int2* __restrict__ epack,
    unsigned short* __restrict__ agg) {     // [2*NB][256] fp16 (aliases d_out)
    __shared__ int2 ebuf[2][CAP];
    __shared__ int soff[2][17];
    const int t = blockIdx.y;
    const int row0 = blockIdx.x * 16;
    const int tid = threadIdx.x;
    const int g = tid >> 4, l16 = tid & 15;
    const int cbase = l16 * 8;          // this lane's 8 fp16 columns

    if (tid < 34) {
        int h = tid / 17, k = tid % 17;
        int rel = h ? (2 + t) : t;
        soff[h][k] = offs[rel * (NB + 1) + row0 + k];
    }
    __syncthreads();

    // stage both relations' edge windows (first CAP each); non-temporal.
    for (int h = 0; h < 2; ++h) {
        int rel = h ? (2 + t) : t;
        const long long* epk =
            reinterpret_cast<const long long*>(epack + (size_t)rel * EB);
        int base = soff[h][0];
        int tot = soff[h][16] - base; if (tot > CAP) tot = CAP;
        for (int i = tid; i < tot; i += 256) {
            long long v = __builtin_nontemporal_load(&epk[base + i]);
            ebuf[h][i] = make_int2((int)(v & 0xffffffffLL), (int)(v >> 32));
        }
    }
    __syncthreads();

    for (int h = 0; h < 2; ++h) {
        int rel = h ? (2 + t) : t;
        const unsigned short* x = xh + (size_t)h * NB * D;
        const int2* epk = epack + (size_t)rel * EB;
        const int base = soff[h][0];
        const int glo = soff[h][g] - base;
        const int ghi0 = soff[h][g + 1] - base;
        const int ghi = ghi0 < CAP ? ghi0 : CAP;   // LDS-resident part
        const int2* eb = ebuf[h];
        float acc[8] = {0.f, 0.f, 0.f, 0.f, 0.f, 0.f, 0.f, 0.f};

        if (glo < ghi) {
            uint4 rA0, rA1, rA2, rA3, rB0, rB1, rB2, rB3;
            float cA0, cA1, cA2, cA3, cB0, cB1, cB2, cB3;
            PREF(glo, cA0, cA1, cA2, cA3, rA0, rA1, rA2, rA3);
            for (int i = glo; i < ghi; i += 8) {
                bool hasB = (i + 4 < ghi);
                if (hasB) PREF(i + 4, cB0, cB1, cB2, cB3, rB0, rB1, rB2, rB3);
                FMA8(cA0, rA0); FMA8(cA1, rA1); FMA8(cA2, rA2); FMA8(cA3, rA3);
                if (i + 8 < ghi) PREF(i + 8, cA0, cA1, cA2, cA3, rA0, rA1, rA2, rA3);
                if (hasB) { FMA8(cB0, rB0); FMA8(cB1, rB1); FMA8(cB2, rB2); FMA8(cB3, rB3); }
            }
        }
        // rare overflow tail straight from global
        for (int i = (glo > CAP ? glo : CAP); i < ghi0; ++i) {
            int2 p = epk[base + i];
            float cc = __int_as_float(p.y);
            uint4 rr = *reinterpret_cast<const uint4*>(x + ((unsigned)p.x * D + cbase));
            FMA8(cc, rr);
        }
        int dg = ghi0 - glo;
        float di = rsqrtf((float)(dg > 1 ? dg : 1));
        u32x4 q;
#pragma unroll
        for (int k2 = 0; k2 < 4; ++k2) {
            unsigned lo2 = __half_as_ushort(__float2half(acc[2 * k2] * di));
            unsigned hi2 = __half_as_ushort(__float2half(acc[2 * k2 + 1] * di));
            q[k2] = lo2 | (hi2 << 16);
        }
        u32x4* dst = reinterpret_cast<u32x4*>(
            agg + ((size_t)(t * NB + row0 + g) * 256 + h * 128 + cbase));
        __builtin_nontemporal_store(q, dst);
    }
}

// Dense MFMA GEMM: out[r][j] = prelu(sum_k agg[r][k] * Wcat_t[k][j] + bias).
__global__ __launch_bounds__(256) void k_gemm(
    const _Float16* agg,                    // aliases out
    const _Float16* __restrict__ Wb,
    const float* __restrict__ b, const float* __restrict__ prelu_a,
    float* out) {
    const int t = blockIdx.y;
    const int tid = threadIdx.x, w = tid >> 6, l = tid & 63;
    const int rbase = t * NB + blockIdx.x * 64 + w * 16;
    const int rmax = t * NB + NB - 1;
    const int lk = (l >> 4) * 8;
    f32x4 acc[8] = {};
    const f16x8* wb = reinterpret_cast<const f16x8*>(Wb + (size_t)t * 32768);
    int ra = rbase + (l & 15); if (ra > rmax) ra = rmax;
    const _Float16* ap = agg + (size_t)ra * 256 + lk;
#pragma unroll
    for (int ks = 0; ks < 8; ++ks) {
        f16x8 a = *reinterpret_cast<const f16x8*>(ap + ks * 32);
#pragma unroll
        for (int jt = 0; jt < 8; ++jt) {
            f16x8 bf = wb[(jt * 8 + ks) * 64 + l];
            acc[jt] = __builtin_amdgcn_mfma_f32_16x16x32_f16(a, bf, acc[jt], 0, 0, 0);
        }
    }
    float pa = prelu_a[0];
    const int rowoff = (l >> 4) * 4;
#pragma unroll
    for (int jt = 0; jt < 8; ++jt) {
        int col = jt * 16 + (l & 15);
        float bs = b[t * D + col] + b[(2 + t) * D + col];
#pragma unroll
        for (int m = 0; m < 4; ++m) {
            int grow = rbase + rowoff + m;
            if (grow <= rmax) {
                float v = acc[jt][m] + bs;
                v = v >= 0.f ? v : pa * v;
                out[(size_t)grow * D + col] = v;
            }
        }
    }
}

extern "C" void kernel_launch(void* const* d_in, const int* in_sizes, int n_in,
                              void* d_out, int out_size, void* d_ws, size_t ws_size,
                              hipStream_t stream) {
    const float* x_drug = (const float*)d_in[0];
    const float* x_dis  = (const float*)d_in[1];
    const float* W      = (const float*)d_in[2];   // [4,128,128]
    const float* b      = (const float*)d_in[3];   // [4,128]
    const float* pa     = (const float*)d_in[4];   // [1]
    EdgePtrs ep;
    ep.src[0] = (const int*)d_in[5];  ep.dst[0] = (const int*)d_in[6];   // dd
    ep.src[1] = (const int*)d_in[7];  ep.dst[1] = (const int*)d_in[8];   // ds
    ep.src[2] = (const int*)d_in[9];  ep.dst[2] = (const int*)d_in[10];  // sd
    ep.src[3] = (const int*)d_in[11]; ep.dst[3] = (const int*)d_in[12];  // ss

    // workspace layout (bytes); no memset needed — all buffers fully written
    char* ws = (char*)d_ws;
    unsigned short* cnt2in = (unsigned short*)(ws + 0);         // [4][16][NB]
    unsigned short* cnt2o  = (unsigned short*)(ws + 6400000);   // [4][16][NB]
    float* coef     = (float*)(ws + 12800000);  // [4][NB]
    int*   offs     = (int*)(ws + 13600000);    // [4][NB+1]
    int*   chunksum = (int*)(ws + 14400064);    // [4][NCH]
    int2*  epack    = (int2*)(ws + 14401664);   // [4][EB] int2 (16 MB)
    unsigned short* xh = (unsigned short*)(ws + 30401664);  // fp16 x (25.6 MB)
    _Float16* Wb    = (_Float16*)(ws + 56001664); // 128 KB packed W
    // total ~56.1 MB

    k_cvt<<<12500, 256, 0, stream>>>(x_drug, x_dis, xh);
    k_hist<<<dim3(NCHK, NRG, 8), 256, 0, stream>>>(ep, cnt2in, cnt2o);
    k_wpack<<<32, 256, 0, stream>>>(W, Wb);
    k_scan1<<<dim3(NCH, 4), 512, 0, stream>>>(cnt2in, cnt2o, coef, offs, chunksum);
    k_scan2<<<1, 256, 0, stream>>>(chunksum);
    k_scan3<<<dim3(NCH, 4), 512, 0, stream>>>(offs, chunksum);
    k_fill3<<<dim3(NCHK, NRG, 4), 256, 0, stream>>>(ep, cnt2in, coef, offs, epack);
    k_gather<<<dim3(NB / 16, 2), 256, 0, stream>>>(
        xh, offs, epack, (unsigned short*)d_out);
    k_gemm<<<dim3(782, 2), 256, 0, stream>>>(
        (const _Float16*)d_out, Wb, b, pa, (float*)d_out);
}